// Round 1
// baseline (146.021 us; speedup 1.0000x reference)
//
#include <hip/hip_runtime.h>
#include <stdint.h>

#define KK 5
#define SCALE_F 50000.0f
#define OC 128
#define IC 128
#define HH 56
#define WW 56
#define NB 64
#define HWSZ (HH * WW)          // 3136
#define NTAP 9
#define NWEL (OC * IC * NTAP)   // 147456

// ---------------------------------------------------------------------------
// Kernel 1: SDP stochastic weight generation + binarize + bit-pack.
// One wave (64 lanes) per (oc, tap, word); lane l -> ic = word*64 + l.
// Packs sign bits via __ballot into wpk[(oc*9 + tap)*2 + word].
// ---------------------------------------------------------------------------
__global__ void __launch_bounds__(256) wpack_kernel(
    const float* __restrict__ M, const float* __restrict__ Z,
    const float* __restrict__ rv, uint64_t* __restrict__ wpk) {
    int gtid = blockIdx.x * blockDim.x + threadIdx.x;
    int lane = gtid & 63;
    int wid  = gtid >> 6;            // 0..2303
    int oc   = wid / 18;
    int r    = wid - oc * 18;
    int tap  = r >> 1;
    int word = r & 1;
    int ic   = word * 64 + lane;
    int idx  = (oc * IC + ic) * NTAP + tap;

    float m  = M[idx];
    float z0 = Z[0 * NWEL + idx];
    float z1 = Z[1 * NWEL + idx];
    float z2 = Z[2 * NWEL + idx];
    float z3 = Z[3 * NWEL + idx];
    float z4 = Z[4 * NWEL + idx];
    // A = m^2 + sum(z^2)/SCALE ; inv = rsqrt(A)
    float s  = z0 * z0 + z1 * z1 + z2 * z2 + z3 * z3 + z4 * z4;
    float A  = m * m + s * (1.0f / SCALE_F);
    float inv = 1.0f / sqrtf(A);
    // w = (rv @ (z*inv)) + m*inv  (match reference op order closely)
    float w = rv[0] * (z0 * inv);
    w += rv[1] * (z1 * inv);
    w += rv[2] * (z2 * inv);
    w += rv[3] * (z3 * inv);
    w += rv[4] * (z4 * inv);
    w += m * inv;

    unsigned long long b = __ballot(w > 0.0f);
    if (lane == 0) wpk[(oc * NTAP + tap) * 2 + word] = b;
}

// ---------------------------------------------------------------------------
// Kernel 2: binarize activations + bit-pack channels.
// One thread per (n, h, w); loops 128 ic (coalesced across threads), builds
// 2x u64, stores 16B. apk layout: [n][hw][2] u64.
// ---------------------------------------------------------------------------
__global__ void __launch_bounds__(256) apack_kernel(
    const float* __restrict__ x, uint64_t* __restrict__ apk) {
    int p  = blockIdx.x * blockDim.x + threadIdx.x;   // 0..200703
    int n  = p / HWSZ;
    int hw = p - n * HWSZ;
    const float* xp = x + (size_t)n * IC * HWSZ + hw;

    uint64_t lo = 0, hi = 0;
#pragma unroll
    for (int c = 0; c < 64; ++c)
        lo |= (uint64_t)(xp[(size_t)c * HWSZ] > 0.0f) << c;
    xp += (size_t)64 * HWSZ;
#pragma unroll
    for (int c = 0; c < 64; ++c)
        hi |= (uint64_t)(xp[(size_t)c * HWSZ] > 0.0f) << c;

    ((ulonglong2*)apk)[p] = make_ulonglong2(lo, hi);
}

// ---------------------------------------------------------------------------
// Kernel 3: XNOR-popcount conv 3x3 pad 1 + alpha scale.
// One thread per (n, h, w) spatial point; loops all 128 oc.
// Weights are wave-uniform (indexed by oc loop var) -> scalar loads (s_load),
// so no LDS pipe pressure. Activation taps held in 18 u64 registers.
// Padding: invalid tap's popc substituted with 64 => contribution 0.
// ---------------------------------------------------------------------------
__global__ void __launch_bounds__(256) bconv_kernel(
    const uint64_t* __restrict__ apk, const uint64_t* __restrict__ wpk,
    const float* __restrict__ alpha, float* __restrict__ out) {
    int p  = blockIdx.x * blockDim.x + threadIdx.x;   // 0..200703
    int n  = p / HWSZ;
    int hw = p - n * HWSZ;
    int h  = hw / WW;
    int w  = hw - h * WW;

    uint64_t alo[NTAP], ahi[NTAP];
    unsigned validm = 0;
    const ulonglong2* ap = (const ulonglong2*)apk + (size_t)n * HWSZ;
#pragma unroll
    for (int t = 0; t < NTAP; ++t) {
        int dh = t / 3 - 1, dw = t % 3 - 1;
        int hh = h + dh, ww2 = w + dw;
        bool v = (hh >= 0) && (hh < HH) && (ww2 >= 0) && (ww2 < WW);
        int addr = v ? (hh * WW + ww2) : hw;   // clamp invalid to self (unused)
        ulonglong2 a = ap[addr];
        alo[t] = a.x;
        ahi[t] = a.y;
        validm |= (unsigned)v << t;
    }

    const ulonglong2* wq = (const ulonglong2*)wpk;
    float* op = out + (size_t)n * OC * HWSZ + hw;
#pragma unroll 4
    for (int oc = 0; oc < OC; ++oc) {
        int cnt = 0;
#pragma unroll
        for (int t = 0; t < NTAP; ++t) {
            ulonglong2 wv = wq[oc * NTAP + t];        // wave-uniform -> s_load
            int pc = __popcll(alo[t] ^ wv.x) + __popcll(ahi[t] ^ wv.y);
            cnt += ((validm >> t) & 1) ? pc : 64;     // invalid tap -> 0 contrib
        }
        op[(size_t)oc * HWSZ] = (float)(NTAP * 128 - 2 * cnt) * alpha[oc];
    }
}

extern "C" void kernel_launch(void* const* d_in, const int* in_sizes, int n_in,
                              void* d_out, int out_size, void* d_ws, size_t ws_size,
                              hipStream_t stream) {
    const float* x     = (const float*)d_in[0];
    const float* M     = (const float*)d_in[1];
    const float* Z     = (const float*)d_in[2];
    const float* Alpha = (const float*)d_in[3];
    const float* rv    = (const float*)d_in[4];
    float* out = (float*)d_out;

    // Workspace layout: [0, 18432) packed weights; [32768, +3.2MB) packed acts.
    uint64_t* wpk = (uint64_t*)d_ws;
    uint64_t* apk = (uint64_t*)((char*)d_ws + 32768);

    // K1: 147456 threads (2304 waves)
    wpack_kernel<<<NWEL / 256, 256, 0, stream>>>(M, Z, rv, wpk);
    // K2: 200704 threads
    apack_kernel<<<(NB * HWSZ) / 256, 256, 0, stream>>>(x, apk);
    // K3: 200704 threads, each computes 128 oc outputs
    bconv_kernel<<<(NB * HWSZ) / 256, 256, 0, stream>>>(apk, wpk, Alpha, out);
}